// Round 13
// baseline (436.686 us; speedup 1.0000x reference)
//
#include <hip/hip_runtime.h>
#include <hip/hip_bf16.h>

#define VOCAB     64
#define D_MODEL   512
#define N_STATE   32
#define H_HEADS   16
#define LAYERS    4
#define D_INNER   1024
#define P_HEAD    64
#define CONV_DIM  1088
#define K_CONV    4
#define D_IN_PROJ 2128
#define NPAD_IN   2176          // 17*128
#define NPAD_HEAD 64
#define BATCH     4
#define SEQ       1024
#define NTOK      (BATCH*SEQ)
#define EPS       1e-5f
#define CL        64            // scan chunk length
#define NC        (SEQ/CL)      // 16 chunks
#define PSTR      80            // padded t-stride (bf16) for transposed LDS tiles

typedef __bf16 bf16x8 __attribute__((ext_vector_type(8)));
typedef float  f32x4  __attribute__((ext_vector_type(4)));

__device__ __forceinline__ float sigmoidf_(float x) { return 1.f / (1.f + __expf(-x)); }
__device__ __forceinline__ float softplusf_(float x) { return (x > 20.f) ? x : log1pf(__expf(x)); }

// async global->LDS, 16B per lane. LDS dest must be linear in lane order.
__device__ __forceinline__ void gload_lds16(const void* g, void* l) {
  __builtin_amdgcn_global_load_lds((const __attribute__((address_space(1))) void*)g,
                                   (__attribute__((address_space(3))) void*)l,
                                   16, 0, 0);
}

// XCD-chunked bijective block remap (MI355X: 8 XCDs, bid%8 = physical XCD).
// Requires gridDim.x % 8 == 0. Consecutive logical ids land on the same XCD,
// pinning shared operand panels (and the ssd conv cache) in that XCD's L2.
// NOTE (R6/R10 lesson): cross-block flag sync INSIDE a dispatch costs ~60us on
// this chip (device-scope fence + acquire polling); producer->consumer transport
// must go through the dispatch boundary + L2-resident memory, as done here.
__device__ __forceinline__ int xcd_lin() {
  return (blockIdx.x & 7) * ((int)gridDim.x >> 3) + ((int)blockIdx.x >> 3);
}

// ---- prep: fused weight transposes (norm weights folded) + embed ----
__global__ __launch_bounds__(256) void prep_kernel(
    const float* __restrict__ W_in, const float* __restrict__ W_out,
    const float* __restrict__ head_w,
    const float* __restrict__ norm_w, const float* __restrict__ gnorm_w,
    __bf16* __restrict__ WtIn, __bf16* __restrict__ WtOut, __bf16* __restrict__ WtHead,
    const int* __restrict__ tok, const float* __restrict__ emb,
    float* __restrict__ h, __bf16* __restrict__ hbf) {
  int b = blockIdx.x;
  if (b >= 6432) {                    // ---- embed part: h = emb[tok], hbf = bf16(h) ----
    int eb = b - 6432;
    int wv = threadIdx.x >> 6, lane = threadIdx.x & 63;
    int tokid = eb * 4 + wv;
    const float* er = emb + (size_t)tok[tokid] * D_MODEL;
    f32x4 v0 = *(const f32x4*)(er + lane * 8);
    f32x4 v1 = *(const f32x4*)(er + lane * 8 + 4);
    float* hr = h + (size_t)tokid * D_MODEL;
    *(f32x4*)(hr + lane * 8) = v0;
    *(f32x4*)(hr + lane * 8 + 4) = v1;
    bf16x8 o8;
    #pragma unroll
    for (int k = 0; k < 4; k++) { o8[k] = (__bf16)v0[k]; o8[4 + k] = (__bf16)v1[k]; }
    *(bf16x8*)(hbf + (size_t)tokid * D_MODEL + lane * 8) = o8;
    return;
  }
  const float* W; const float* fold; __bf16* Wt; int K, N, Npad, bx, by;
  if (b < 4352) {                     // in_proj: 4 layers x (68 x 16), fold norm_w over K
    int z = b / 1088, r = b % 1088;
    bx = r % 68; by = r / 68;
    W = W_in + (size_t)z * D_MODEL * D_IN_PROJ;
    fold = norm_w + (size_t)z * D_MODEL;
    Wt = WtIn + (size_t)z * NPAD_IN * D_MODEL;
    K = D_MODEL; N = D_IN_PROJ; Npad = NPAD_IN;
  } else if (b < 6400) {              // out_proj: 4 layers x (16 x 32), fold gnorm_w over K
    int r = b - 4352; int z = r / 512; r %= 512;
    bx = r % 16; by = r / 16;
    W = W_out + (size_t)z * D_INNER * D_MODEL;
    fold = gnorm_w + (size_t)z * D_INNER;
    Wt = WtOut + (size_t)z * D_MODEL * D_INNER;
    K = D_INNER; N = D_MODEL; Npad = D_MODEL;
  } else {                            // head: 2 x 16, no fold
    int r = b - 6400;
    bx = r % 2; by = r / 2;
    W = head_w; fold = nullptr; Wt = WtHead;
    K = D_MODEL; N = VOCAB; Npad = NPAD_HEAD;
  }
  __shared__ float T[32][33];
  int n0 = bx * 32, k0 = by * 32;
  int tx = threadIdx.x & 31, ty = threadIdx.x >> 5;  // ty 0..7
  #pragma unroll
  for (int i = 0; i < 4; i++) {
    int n = n0 + tx;
    T[ty + i * 8][tx] = (n < N) ? W[(size_t)(k0 + ty + i * 8) * N + n] : 0.f;
  }
  __syncthreads();
  float fs = fold ? fold[k0 + tx] : 1.f;
  #pragma unroll
  for (int i = 0; i < 4; i++)
    Wt[(size_t)(n0 + ty + i * 8) * K + k0 + tx] = (__bf16)(T[tx][ty + i * 8] * fs);
}

// ------- bf16 MFMA GEMM, 64x32 tile, TRI-buffered depth-2 pipeline (out_proj / head) -------
// Longest-K kernel: depth-2 counted vmcnt keeps 2 tiles in flight across barriers.
// 3 gloads/thread per stage (A 2 + B 1): steady vmcnt(6), drain vmcnt(3)/(0).
// LDS 3x12KB=36KB -> 4 blocks/CU; grid 1024 (out_proj) = full single scheduling round.
#define TK 64
__global__ __launch_bounds__(256) void gemm64_kernel(
    const __bf16* __restrict__ A, const __bf16* __restrict__ Bt,
    const float* __restrict__ bias, const float* __restrict__ res,
    float* __restrict__ C, __bf16* __restrict__ Cbf,
    float inv_norm_dim, int nbx, int K, int N, int ldc) {
  __shared__ __bf16 As[3][64 * TK];
  __shared__ __bf16 Bs[3][32 * TK];
  int tid = threadIdx.x;
  int lane = tid & 63, wave = tid >> 6;
  int wm = wave >> 1, wn = wave & 1;        // wm 0..1 (row half), wn 0..1 (16-col half)
  int q = lane >> 4, l16 = lane & 15;
  int lin = xcd_lin();
  int bx = lin % nbx, by = lin / nbx;
  size_t row0 = (size_t)by * 64;
  int col0 = bx * 32;
  const __bf16* Ab = A + row0 * K;
  const __bf16* Bb = Bt + (size_t)col0 * K;

  auto stage = [&](int buf, int kk) {
    #pragma unroll
    for (int r = 0; r < 2; r++) {           // A: 64 rows x 64 K = 8KB = 2 x 16B/thread
      int lin2 = r * 256 + tid;
      gload_lds16(Ab + (size_t)(lin2 >> 3) * K + kk + (lin2 & 7) * 8, &As[buf][lin2 * 8]);
    }
    {                                        // B: 32 rows x 64 K = 4KB = 1 x 16B/thread
      int lin2 = tid;
      gload_lds16(Bb + (size_t)(lin2 >> 3) * K + kk + (lin2 & 7) * 8, &Bs[buf][lin2 * 8]);
    }
  };

  f32x4 acc[2];
  acc[0] = (f32x4){0.f, 0.f, 0.f, 0.f};
  acc[1] = (f32x4){0.f, 0.f, 0.f, 0.f};
  float ssqa[2] = {0.f, 0.f};

  int niter = K / TK;
  stage(0, 0);
  if (niter > 1) stage(1, TK);
  int bi = 0;
  for (int i = 0; i < niter; i++) {
    if (i + 2 < niter) {
      stage((bi + 2) % 3, (i + 2) * TK);    // issue 2 ahead
      asm volatile("s_waitcnt vmcnt(6)" ::: "memory");   // tile i done; i+1,i+2 in flight
    } else if (i + 1 < niter) {
      asm volatile("s_waitcnt vmcnt(3)" ::: "memory");   // tile i done; i+1 in flight
    } else {
      asm volatile("s_waitcnt vmcnt(0)" ::: "memory");
    }
    __builtin_amdgcn_s_barrier();
    #pragma unroll
    for (int ks = 0; ks < 2; ks++) {
      bf16x8 af[2], bfv;
      #pragma unroll
      for (int ii = 0; ii < 2; ii++) {
        af[ii] = *(const bf16x8*)(&As[bi][(wm * 32 + ii * 16 + l16) * TK + ks * 32 + q * 8]);
        #pragma unroll
        for (int k = 0; k < 8; k++) { float v = (float)af[ii][k]; ssqa[ii] += v * v; }
      }
      bfv = *(const bf16x8*)(&Bs[bi][(wn * 16 + l16) * TK + ks * 32 + q * 8]);
      #pragma unroll
      for (int ii = 0; ii < 2; ii++)
        acc[ii] = __builtin_amdgcn_mfma_f32_16x16x32_bf16(af[ii], bfv, acc[ii], 0, 0, 0);
    }
    __builtin_amdgcn_s_barrier();           // all reads of slot bi done before its re-stage
    bi = (bi + 1) % 3;
  }

  #pragma unroll
  for (int i = 0; i < 2; i++) {
    ssqa[i] += __shfl_xor(ssqa[i], 16);
    ssqa[i] += __shfl_xor(ssqa[i], 32);     // full row sum for row wm*32+i*16+l16
  }
  #pragma unroll
  for (int i = 0; i < 2; i++) {
    #pragma unroll
    for (int rr = 0; rr < 4; rr++) {
      size_t mrow = row0 + wm * 32 + i * 16 + q * 4 + rr;
      float sq = __shfl(ssqa[i], q * 4 + rr);
      float sc = (inv_norm_dim > 0.f) ? rsqrtf(sq * inv_norm_dim + EPS) : 1.f;
      int col = col0 + wn * 16 + l16;
      if (col < N) {
        size_t off = mrow * (size_t)ldc + col;
        float v = acc[i][rr] * sc + (bias ? bias[col] : 0.f);
        if (res) v += res[off];
        if (C)   C[off] = v;
        if (Cbf) Cbf[off] = (__bf16)v;
      }
    }
  }
}

// ------- bf16 MFMA GEMM, 64x128 tile, K-step 32, TRI-buffered depth-2 (in_proj) -------
// Same pipeline structure as gemm64 (proven R12): 3 gloads/thread per stage (A 1 + B 2),
// stage k+2 issued each iteration, steady vmcnt(6), drain vmcnt(3)/(0).
// LDS 3x(4+8)KB = 36KB -> 4 blocks/CU; grid 1088 ~ one full scheduling round.
// rmsnorm fused via in-kernel row-ssq; epilogue repacked through LDS -> bf16x8 stores
#define TKI 32
__global__ __launch_bounds__(256) void gemm_in_kernel(
    const __bf16* __restrict__ A, const __bf16* __restrict__ Bt,
    const float* __restrict__ bias, __bf16* __restrict__ Cbf,
    int nbx, int K, int N, int ldc) {
  __shared__ __bf16 As[3][64 * TKI];
  __shared__ __bf16 Bs[3][128 * TKI];
  int tid = threadIdx.x;
  int lane = tid & 63, wave = tid >> 6;
  int wm = wave >> 1, wn = wave & 1;
  int q = lane >> 4, l16 = lane & 15;
  int lin = xcd_lin();
  int bx = lin % nbx, by = lin / nbx;
  size_t row0 = (size_t)by * 64;
  int col0 = bx * 128;
  const __bf16* Ab = A + row0 * K;
  const __bf16* Bb = Bt + (size_t)col0 * K;

  auto stage = [&](int buf, int kk) {
    {                                        // A: 64 rows x 32 K = 4KB = 1 x 16B/thread
      gload_lds16(Ab + (size_t)(tid >> 2) * K + kk + (tid & 3) * 8, &As[buf][tid * 8]);
    }
    #pragma unroll
    for (int r = 0; r < 2; r++) {            // B: 128 rows x 32 K = 8KB = 2 x 16B/thread
      int lin2 = r * 256 + tid;
      gload_lds16(Bb + (size_t)(lin2 >> 2) * K + kk + (lin2 & 3) * 8, &Bs[buf][lin2 * 8]);
    }
  };

  f32x4 acc[2][4];
  #pragma unroll
  for (int i = 0; i < 2; i++)
    #pragma unroll
    for (int j = 0; j < 4; j++) acc[i][j] = (f32x4){0.f, 0.f, 0.f, 0.f};
  float ssqa[2] = {0.f, 0.f};

  int niter = K / TKI;                       // 16
  stage(0, 0);
  stage(1, TKI);
  int bi = 0;
  for (int i = 0; i < niter; i++) {
    if (i + 2 < niter) {
      stage((bi + 2) % 3, (i + 2) * TKI);   // issue 2 ahead
      asm volatile("s_waitcnt vmcnt(6)" ::: "memory");   // tile i done; i+1,i+2 in flight
    } else if (i + 1 < niter) {
      asm volatile("s_waitcnt vmcnt(3)" ::: "memory");
    } else {
      asm volatile("s_waitcnt vmcnt(0)" ::: "memory");
    }
    __builtin_amdgcn_s_barrier();
    {
      bf16x8 af[2], bfv[4];
      #pragma unroll
      for (int ii = 0; ii < 2; ii++) {
        af[ii] = *(const bf16x8*)(&As[bi][(wm * 32 + ii * 16 + l16) * TKI + q * 8]);
        #pragma unroll
        for (int k = 0; k < 8; k++) { float v = (float)af[ii][k]; ssqa[ii] += v * v; }
      }
      #pragma unroll
      for (int j = 0; j < 4; j++)
        bfv[j] = *(const bf16x8*)(&Bs[bi][(wn * 64 + j * 16 + l16) * TKI + q * 8]);
      #pragma unroll
      for (int ii = 0; ii < 2; ii++)
        #pragma unroll
        for (int j = 0; j < 4; j++)
          acc[ii][j] = __builtin_amdgcn_mfma_f32_16x16x32_bf16(af[ii], bfv[j], acc[ii][j], 0, 0, 0);
    }
    __builtin_amdgcn_s_barrier();           // all reads of slot bi done before its re-stage
    bi = (bi + 1) % 3;
  }

  #pragma unroll
  for (int i = 0; i < 2; i++) {
    ssqa[i] += __shfl_xor(ssqa[i], 16);
    ssqa[i] += __shfl_xor(ssqa[i], 32);
  }
  // epilogue: scale+bias -> LDS (bf16) -> coalesced bf16x8 stores
  __bf16* Cs = (__bf16*)Bs;            // dead; 64x136 = 17408 B fits in Bs (24KB)
  const int CST = 136;
  float bvj[4];
  #pragma unroll
  for (int j = 0; j < 4; j++) {
    int colj = col0 + wn * 64 + j * 16 + l16;
    bvj[j] = (colj < N) ? bias[colj] : 0.f;
  }
  #pragma unroll
  for (int i = 0; i < 2; i++) {
    #pragma unroll
    for (int rr = 0; rr < 4; rr++) {
      int rloc = wm * 32 + i * 16 + q * 4 + rr;
      float sq = __shfl(ssqa[i], q * 4 + rr);
      float sc = rsqrtf(sq * (1.f / D_MODEL) + EPS);
      #pragma unroll
      for (int j = 0; j < 4; j++)
        Cs[rloc * CST + wn * 64 + j * 16 + l16] = (__bf16)(acc[i][j][rr] * sc + bvj[j]);
    }
  }
  __syncthreads();
  #pragma unroll
  for (int s = 0; s < 2; s++) {
    int idx = s * 256 + tid;
    int row = idx >> 3, c0 = (idx & 7) * 16;
    if (col0 + c0 < N) {
      bf16x8 v0 = *(const bf16x8*)(&Cs[row * CST + c0]);
      bf16x8 v1 = *(const bf16x8*)(&Cs[row * CST + c0 + 8]);
      __bf16* dst = Cbf + (row0 + row) * (size_t)ldc + col0 + c0;
      *(bf16x8*)dst = v0;
      *(bf16x8*)(dst + 8) = v1;
    }
  }
}

// ================= MFMA chunked SSD (split pair, conv once, image-layout cache) =================
// zxbf row: [z 0..1024 | x 1024..2048 | B 2048..2080 | C 2080..2112 | dt 2112..2128]
// ssd_local: conv/silu + dt-cumsum; caches conv outputs as EXACT LDS IMAGES
// (lxT padded [64][PSTR]; lB|lC contiguous [64][32]x2) so ssd_out can DMA them
// linearly with global_load_lds; publishes Slocal (chunks 0..NC-2 only; Slocal of the
// last chunk is never read) + dAprod.
// ssd_out: async-stages the images, overlaps the chunk-start scan with the DMA.
__device__ __forceinline__ void wave0_dt_cumsum(
    const __bf16* __restrict__ zxbf, const float* __restrict__ dt_bias,
    int b, int h, int t0, int tid, float* ldt, float* lcs, float* __restrict__ dtcsg) {
  if (tid < 64) {
    float dv = (float)zxbf[((size_t)(b * SEQ + t0 + tid)) * D_IN_PROJ + 2 * D_INNER + 2 * N_STATE + h]
               + dt_bias[h];
    float dtv = softplusf_(dv);
    float cs = dtv;
    #pragma unroll
    for (int off = 1; off < 64; off <<= 1) {
      float o = __shfl_up(cs, off);
      if (tid >= off) cs += o;
    }
    ldt[tid] = dtv;
    lcs[tid] = cs;
    dtcsg[tid] = dtv;
    dtcsg[64 + tid] = cs;
  }
}

__global__ __launch_bounds__(256) void ssd_local_kernel(
    const __bf16* __restrict__ zxbf, const float* __restrict__ conv_w,
    const float* __restrict__ conv_b, const float* __restrict__ dt_bias,
    const float* __restrict__ A_log,
    float* __restrict__ Slocal, float* __restrict__ dAprod,
    __bf16* __restrict__ convx, __bf16* __restrict__ convbc, float* __restrict__ dtcs) {
  int blk = xcd_lin();
  int c = blk % NC;
  int h = (blk / NC) % H_HEADS;
  int b = blk / (NC * H_HEADS);
  int tid = threadIdx.x;
  int lane = tid & 63, wave = tid >> 6;
  int q = lane >> 4, l16 = lane & 15;
  int t0 = c * CL;
  float A = -__expf(A_log[h]);
  __shared__ __bf16 rawbuf[2 * 68 * 64];   // rawx | rawBC; reused as f32 sT[64][36]
  __shared__ __bf16 lxT[64][PSTR];
  __shared__ __bf16 lBTw[32][PSTR];
  __shared__ float ldt[64], lcs[64];
  __bf16* rawx = rawbuf;
  __bf16* rawBC = rawbuf + 68 * 64;
  for (int i = tid; i < 68 * 8; i += 256) {
    int r = i >> 3, c0 = (i & 7) * 8;
    int gr = t0 - 3 + r;
    bf16x8 vx, vbc;
    #pragma unroll
    for (int k = 0; k < 8; k++) { vx[k] = (__bf16)0.f; vbc[k] = (__bf16)0.f; }
    if (gr >= 0) {
      const __bf16* rowp = zxbf + ((size_t)(b * SEQ + gr)) * D_IN_PROJ;
      vx  = *(const bf16x8*)(rowp + D_INNER + h * 64 + c0);
      vbc = *(const bf16x8*)(rowp + 2 * D_INNER + c0);
    }
    *(bf16x8*)(rawx + r * 64 + c0)  = vx;
    *(bf16x8*)(rawBC + r * 64 + c0) = vbc;
  }
  wave0_dt_cumsum(zxbf, dt_bias, b, h, t0, tid, ldt, lcs, dtcs + (size_t)blk * 128);
  __syncthreads();
  float cs63 = lcs[63];
  __bf16* xg  = convx  + (size_t)blk * (64 * PSTR);
  __bf16* bcg = convbc + (size_t)blk * 4096;
  // conv x -> lxT (transposed, silu)
  {
    int p = tid & 63;
    const float* w = conv_w + (h * 64 + p) * K_CONV;
    float w0 = w[0], w1 = w[1], w2 = w[2], w3 = w[3];
    float cb = conv_b[h * 64 + p];
    for (int i = tid; i < CL * 64; i += 256) {
      int t = i >> 6;
      float a = cb + w0 * (float)rawx[t * 64 + p] + w1 * (float)rawx[(t + 1) * 64 + p]
                   + w2 * (float)rawx[(t + 2) * 64 + p] + w3 * (float)rawx[(t + 3) * 64 + p];
      lxT[p][t] = (__bf16)(a * sigmoidf_(a));
    }
  }
  // conv B,C -> cache image (row-major); B also weighted into lBTw for the Slocal MFMA
  {
    int col = tid & 63;
    const float* w = conv_w + (D_INNER + col) * K_CONV;
    float w0 = w[0], w1 = w[1], w2 = w[2], w3 = w[3];
    float cb = conv_b[D_INNER + col];
    for (int i = tid; i < CL * 64; i += 256) {
      int t = i >> 6;
      float a = cb + w0 * (float)rawBC[t * 64 + col] + w1 * (float)rawBC[(t + 1) * 64 + col]
                   + w2 * (float)rawBC[(t + 2) * 64 + col] + w3 * (float)rawBC[(t + 3) * 64 + col];
      float v = a * sigmoidf_(a);
      if (col < 32) {
        bcg[t * 32 + col] = (__bf16)v;
        float wt = ldt[t] * __expf(A * (cs63 - lcs[t]));
        lBTw[col][t] = (__bf16)(v * wt);
      } else {
        bcg[2048 + t * 32 + (col - 32)] = (__bf16)v;
      }
    }
  }
  __syncthreads();
  // cache the padded lxT image verbatim (incl. pad bytes; never read)
  for (int i = tid; i < (64 * PSTR) / 8; i += 256)
    *(bf16x8*)(xg + i * 8) = *(const bf16x8*)(((const __bf16*)lxT) + i * 8);
  // Slocal = xT(weighted-B)^T via MFMA -- only chunks whose Slocal is ever read (c < NC-1)
  if (c < NC - 1) {
    f32x4 acc0 = (f32x4){0.f,0.f,0.f,0.f}, acc1 = (f32x4){0.f,0.f,0.f,0.f};
    #pragma unroll
    for (int kb = 0; kb < 2; kb++) {
      bf16x8 af = *(const bf16x8*)(&lxT[wave * 16 + l16][kb * 32 + q * 8]);
      bf16x8 b0 = *(const bf16x8*)(&lBTw[l16][kb * 32 + q * 8]);
      bf16x8 b1 = *(const bf16x8*)(&lBTw[l16 + 16][kb * 32 + q * 8]);
      acc0 = __builtin_amdgcn_mfma_f32_16x16x32_bf16(af, b0, acc0, 0, 0, 0);
      acc1 = __builtin_amdgcn_mfma_f32_16x16x32_bf16(af, b1, acc1, 0, 0, 0);
    }
    // LDS bounce (wave-private rows) -> f32x4 stores
    float* sT = (float*)rawbuf;
    #pragma unroll
    for (int rr = 0; rr < 4; rr++) {
      int p = wave * 16 + q * 4 + rr;
      sT[p * 36 + l16]      = acc0[rr];
      sT[p * 36 + l16 + 16] = acc1[rr];
    }
    int row = tid >> 2, c0 = (tid & 3) * 8;
    f32x4 a = *(const f32x4*)(sT + row * 36 + c0);
    f32x4 b2 = *(const f32x4*)(sT + row * 36 + c0 + 4);
    float* dstp = Slocal + (size_t)blk * 2048 + row * 32 + c0;
    *(f32x4*)dstp = a;
    *(f32x4*)(dstp + 4) = b2;
  }
  if (tid == 0) dAprod[blk] = __expf(A * cs63);
}

__global__ __launch_bounds__(256) void ssd_out_kernel(
    const __bf16* __restrict__ zxbf, const float* __restrict__ A_log,
    const float* __restrict__ Dp,
    const float* __restrict__ Slocal, const float* __restrict__ dAprod,
    const __bf16* __restrict__ convx, const __bf16* __restrict__ convbc,
    const float* __restrict__ dtcs, __bf16* __restrict__ gout) {
  int blk = xcd_lin();
  int c = blk % NC;
  int h = (blk / NC) % H_HEADS;
  int b = blk / (NC * H_HEADS);
  int tid = threadIdx.x;
  int lane = tid & 63, wave = tid >> 6;
  int q = lane >> 4, l16 = lane & 15;
  int t0 = c * CL;
  float A = -__expf(A_log[h]);
  float D = Dp[h];
  __shared__ __bf16 lxT[64][PSTR];
  __shared__ __bf16 pPbuf[64 * PSTR];       // per-wave P slabs; reused as yT[64][72]
  __shared__ __bf16 lBC[2 * 64 * 32];       // lB | lC contiguous (matches bcg image)
  __shared__ __bf16 lS[64][32];
  __shared__ float ldt[64], lcs[64];
  const __bf16* xg  = convx  + (size_t)blk * (64 * PSTR);
  const __bf16* bcg = convbc + (size_t)blk * 4096;
  __bf16* lB = lBC;
  __bf16* lC = lBC + 2048;
  // async DMA the conv-cache images into LDS (linear dest, wave-contiguous)
  for (int i = tid; i < (64 * PSTR) / 8; i += 256)
    gload_lds16(xg + i * 8, ((__bf16*)lxT) + i * 8);
  for (int i = tid; i < 512; i += 256)
    gload_lds16(bcg + i * 8, lBC + i * 8);
  // overlap: small loads + the serial prefix scan hide the DMA latency
  if (tid < 64) {
    const float* dg = dtcs + (size_t)blk * 128;
    ldt[tid] = dg[tid];
    lcs[tid] = dg[64 + tid];
  }
  // chunk-start scan: Sstart_c = scan over Slocal chunks j<c.
  // dAprod read directly from global per thread (L2-hot broadcast) -- no LDS pr[]
  // (an LDS pr[] here would need a barrier, which would drain the DMA early; direct
  // loads keep the DMA overlapped AND avoid the cross-thread race).
  {
    int p = tid >> 2, n0 = (tid & 3) * 8;
    const float* sl = Slocal + (size_t)(blk - c) * 2048 + p * 32 + n0;
    const float* dab = dAprod + (blk - c);
    float st[8] = {};
    for (int j = 0; j < c; j++) {
      f32x4 a = *(const f32x4*)(sl + (size_t)j * 2048);
      f32x4 bq = *(const f32x4*)(sl + (size_t)j * 2048 + 4);
      float prj = dab[j];
      #pragma unroll
      for (int k = 0; k < 4; k++) { st[k] = prj * st[k] + a[k]; st[4 + k] = prj * st[4 + k] + bq[k]; }
    }
    #pragma unroll
    for (int k = 0; k < 8; k++) lS[p][n0 + k] = (__bf16)st[k];
  }
  __syncthreads();   // drains DMA (vmcnt) + all LDS writes
  bf16x8 afC = *(const bf16x8*)(lC + (wave * 16 + l16) * 32 + q * 8);
  f32x4 accG[4], accI[4], accY[4];
  #pragma unroll
  for (int j = 0; j < 4; j++) {
    accG[j] = (f32x4){0.f,0.f,0.f,0.f};
    accI[j] = (f32x4){0.f,0.f,0.f,0.f};
    accY[j] = (f32x4){0.f,0.f,0.f,0.f};
  }
  #pragma unroll
  for (int j = 0; j < 4; j++) {
    bf16x8 bf = *(const bf16x8*)(lB + (l16 + 16 * j) * 32 + q * 8);
    accG[j] = __builtin_amdgcn_mfma_f32_16x16x32_bf16(afC, bf, accG[j], 0, 0, 0);
  }
  #pragma unroll
  for (int j = 0; j < 4; j++) {
    bf16x8 bf = *(const bf16x8*)(&lS[l16 + 16 * j][q * 8]);
    accI[j] = __builtin_amdgcn_mfma_f32_16x16x32_bf16(afC, bf, accI[j], 0, 0, 0);
  }
  __bf16* pP = pPbuf + wave * 16 * PSTR;    // wave-private slab
  #pragma unroll
  for (int j = 0; j < 4; j++) {
    int s = l16 + 16 * j;
    float css = lcs[s], dts = ldt[s];
    #pragma unroll
    for (int rr = 0; rr < 4; rr++) {
      int tl = q * 4 + rr;
      int t = wave * 16 + tl;
      float val = accG[j][rr] * __expf(A * (lcs[t] - css)) * dts;
      if (s == t) val += D;
      if (s > t) val = 0.f;
      pP[tl * PSTR + s] = (__bf16)val;
    }
  }
  #pragma unroll
  for (int kb = 0; kb < 2; kb++) {
    bf16x8 afP = *(const bf16x8*)(pP + l16 * PSTR + kb * 32 + q * 8);
    #pragma unroll
    for (int j = 0; j < 4; j++) {
      bf16x8 bf = *(const bf16x8*)(&lxT[l16 + 16 * j][kb * 32 + q * 8]);
      accY[j] = __builtin_amdgcn_mfma_f32_16x16x32_bf16(afP, bf, accY[j], 0, 0, 0);
    }
  }
  // y tile via LDS bounce (yT[64][72] over pPbuf; barrier: yT overlaps other waves' pP)
  __syncthreads();
  __bf16* yT = pPbuf;
  #pragma unroll
  for (int rr = 0; rr < 4; rr++) {
    int t = wave * 16 + q * 4 + rr;
    float cumt = __expf(A * lcs[t]);
    #pragma unroll
    for (int j = 0; j < 4; j++) {
      int p = l16 + 16 * j;
      yT[t * 72 + p] = (__bf16)(accY[j][rr] + cumt * accI[j][rr]);
    }
  }
  {
    int row = tid >> 2, col0 = (tid & 3) * 16;   // rows wave-private: no barrier needed
    bf16x8 y0 = *(const bf16x8*)(yT + row * 72 + col0);
    bf16x8 y1 = *(const bf16x8*)(yT + row * 72 + col0 + 8);
    const __bf16* zrow = zxbf + ((size_t)(b * SEQ + t0 + row)) * D_IN_PROJ + h * 64 + col0;
    bf16x8 z0 = *(const bf16x8*)zrow;
    bf16x8 z1 = *(const bf16x8*)(zrow + 8);
    bf16x8 g0, g1;
    #pragma unroll
    for (int k = 0; k < 8; k++) {
      float zz = (float)z0[k];
      g0[k] = (__bf16)((float)y0[k] * zz * sigmoidf_(zz));
    }
    #pragma unroll
    for (int k = 0; k < 8; k++) {
      float zz = (float)z1[k];
      g1[k] = (__bf16)((float)y1[k] * zz * sigmoidf_(zz));
    }
    __bf16* grow = gout + ((size_t)(b * SEQ + t0 + row)) * D_INNER + h * 64 + col0;
    *(bf16x8*)grow = g0;
    *(bf16x8*)(grow + 8) = g1;
  }
}

extern "C" void kernel_launch(void* const* d_in, const int* in_sizes, int n_in,
                              void* d_out, int out_size, void* d_ws, size_t ws_size,
                              hipStream_t stream) {
  const int*   tok     = (const int*)  d_in[0];
  const float* emb     = (const float*)d_in[1];
  const float* norm_w  = (const float*)d_in[2];
  const float* W_in    = (const float*)d_in[3];
  const float* b_in    = (const float*)d_in[4];
  const float* conv_w  = (const float*)d_in[5];
  const float* conv_b  = (const float*)d_in[6];
  const float* dt_bias = (const float*)d_in[7];
  const float* A_log   = (const float*)d_in[8];
  const float* D_par   = (const float*)d_in[9];
  const float* gnorm_w = (const float*)d_in[10];
  const float* W_out   = (const float*)d_in[11];
  const float* b_out   = (const float*)d_in[12];
  const float* head_w  = (const float*)d_in[13];
  const float* head_b  = (const float*)d_in[14];
  float* out = (float*)d_out;

  char* p = (char*)d_ws;
  auto alloc = [&](size_t bytes) { void* r = (void*)p; p += (bytes + 255) & ~(size_t)255; return r; };
  float*  h      = (float*) alloc((size_t)NTOK * D_MODEL * 4);
  float*  slocal = (float*) alloc((size_t)BATCH * H_HEADS * NC * P_HEAD * N_STATE * 4);
  float*  daprod = (float*) alloc((size_t)BATCH * H_HEADS * NC * 4);
  float*  dtcs   = (float*) alloc((size_t)1024 * 128 * 4);
  __bf16* convx  = (__bf16*)alloc((size_t)1024 * 64 * PSTR * 2);
  __bf16* convbc = (__bf16*)alloc((size_t)1024 * 4096 * 2);
  __bf16* zxbf   = (__bf16*)alloc((size_t)NTOK * D_IN_PROJ * 2);
  __bf16* gbf    = (__bf16*)alloc((size_t)NTOK * D_INNER * 2);
  __bf16* hbf    = (__bf16*)alloc((size_t)NTOK * D_MODEL * 2);
  __bf16* WtIn   = (__bf16*)alloc((size_t)LAYERS * NPAD_IN * D_MODEL * 2);
  __bf16* WtOut  = (__bf16*)alloc((size_t)LAYERS * D_MODEL * D_INNER * 2);
  __bf16* WtHead = (__bf16*)alloc((size_t)NPAD_HEAD * D_MODEL * 2);

  prep_kernel<<<6432 + NTOK / 4, 256, 0, stream>>>(
      W_in, W_out, head_w, norm_w, gnorm_w, WtIn, WtOut, WtHead,
      tok, emb, h, hbf);

  for (int l = 0; l < LAYERS; l++) {
    gemm_in_kernel<<<1088, 256, 0, stream>>>(
        hbf, WtIn + (size_t)l * NPAD_IN * D_MODEL, b_in + (size_t)l * D_IN_PROJ,
        zxbf, NPAD_IN / 128, D_MODEL, D_IN_PROJ, D_IN_PROJ);

    ssd_local_kernel<<<BATCH * H_HEADS * NC, 256, 0, stream>>>(
        zxbf, conv_w + (size_t)l * CONV_DIM * K_CONV, conv_b + (size_t)l * CONV_DIM,
        dt_bias + (size_t)l * H_HEADS, A_log + (size_t)l * H_HEADS, slocal, daprod,
        convx, convbc, dtcs);
    ssd_out_kernel<<<BATCH * H_HEADS * NC, 256, 0, stream>>>(
        zxbf, A_log + (size_t)l * H_HEADS, D_par + (size_t)l * H_HEADS,
        slocal, daprod, convx, convbc, dtcs, gbf);

    // out_proj: grid 1024 = 4 blocks/CU, 64x32 tiles, depth-2 pipeline
    gemm64_kernel<<<1024, 256, 0, stream>>>(
        gbf, WtOut + (size_t)l * D_MODEL * D_INNER, b_out + (size_t)l * D_MODEL, h,
        h, hbf, 1.f / D_INNER, D_MODEL / 32, D_INNER, D_MODEL, D_MODEL);
  }

  // head: grid 128, 64x32 tiles
  gemm64_kernel<<<128, 256, 0, stream>>>(
      hbf, WtHead, head_b, nullptr, out, nullptr, 0.f, NPAD_HEAD / 32, D_MODEL, VOCAB, VOCAB);
}

// Round 14
// 431.321 us; speedup vs baseline: 1.0124x; 1.0124x over previous
//
#include <hip/hip_runtime.h>
#include <hip/hip_bf16.h>

#define VOCAB     64
#define D_MODEL   512
#define N_STATE   32
#define H_HEADS   16
#define LAYERS    4
#define D_INNER   1024
#define P_HEAD    64
#define CONV_DIM  1088
#define K_CONV    4
#define D_IN_PROJ 2128
#define NPAD_IN   2176          // 17*128
#define NPAD_HEAD 64
#define BATCH     4
#define SEQ       1024
#define NTOK      (BATCH*SEQ)
#define EPS       1e-5f
#define CL        64            // scan chunk length
#define NC        (SEQ/CL)      // 16 chunks
#define PSTR      80            // padded t-stride (bf16) for transposed LDS tiles

typedef __bf16 bf16x8 __attribute__((ext_vector_type(8)));
typedef float  f32x4  __attribute__((ext_vector_type(4)));

__device__ __forceinline__ float sigmoidf_(float x) { return 1.f / (1.f + __expf(-x)); }
__device__ __forceinline__ float softplusf_(float x) { return (x > 20.f) ? x : log1pf(__expf(x)); }

// async global->LDS, 16B per lane. LDS dest must be linear in lane order.
__device__ __forceinline__ void gload_lds16(const void* g, void* l) {
  __builtin_amdgcn_global_load_lds((const __attribute__((address_space(1))) void*)g,
                                   (__attribute__((address_space(3))) void*)l,
                                   16, 0, 0);
}

// XCD-chunked bijective block remap (MI355X: 8 XCDs, bid%8 = physical XCD).
// Requires gridDim.x % 8 == 0. Consecutive logical ids land on the same XCD,
// pinning shared operand panels (and the ssd conv cache) in that XCD's L2.
// NOTE (R6/R10 lesson): cross-block flag sync INSIDE a dispatch costs ~60us on
// this chip (device-scope fence + acquire polling); producer->consumer transport
// must go through the dispatch boundary + L2-resident memory, as done here.
__device__ __forceinline__ int xcd_lin() {
  return (blockIdx.x & 7) * ((int)gridDim.x >> 3) + ((int)blockIdx.x >> 3);
}

// ---- prep: fused weight transposes (norm weights folded) + embed ----
__global__ __launch_bounds__(256) void prep_kernel(
    const float* __restrict__ W_in, const float* __restrict__ W_out,
    const float* __restrict__ head_w,
    const float* __restrict__ norm_w, const float* __restrict__ gnorm_w,
    __bf16* __restrict__ WtIn, __bf16* __restrict__ WtOut, __bf16* __restrict__ WtHead,
    const int* __restrict__ tok, const float* __restrict__ emb,
    float* __restrict__ h, __bf16* __restrict__ hbf) {
  int b = blockIdx.x;
  if (b >= 6432) {                    // ---- embed part: h = emb[tok], hbf = bf16(h) ----
    int eb = b - 6432;
    int wv = threadIdx.x >> 6, lane = threadIdx.x & 63;
    int tokid = eb * 4 + wv;
    const float* er = emb + (size_t)tok[tokid] * D_MODEL;
    f32x4 v0 = *(const f32x4*)(er + lane * 8);
    f32x4 v1 = *(const f32x4*)(er + lane * 8 + 4);
    float* hr = h + (size_t)tokid * D_MODEL;
    *(f32x4*)(hr + lane * 8) = v0;
    *(f32x4*)(hr + lane * 8 + 4) = v1;
    bf16x8 o8;
    #pragma unroll
    for (int k = 0; k < 4; k++) { o8[k] = (__bf16)v0[k]; o8[4 + k] = (__bf16)v1[k]; }
    *(bf16x8*)(hbf + (size_t)tokid * D_MODEL + lane * 8) = o8;
    return;
  }
  const float* W; const float* fold; __bf16* Wt; int K, N, Npad, bx, by;
  if (b < 4352) {                     // in_proj: 4 layers x (68 x 16), fold norm_w over K
    int z = b / 1088, r = b % 1088;
    bx = r % 68; by = r / 68;
    W = W_in + (size_t)z * D_MODEL * D_IN_PROJ;
    fold = norm_w + (size_t)z * D_MODEL;
    Wt = WtIn + (size_t)z * NPAD_IN * D_MODEL;
    K = D_MODEL; N = D_IN_PROJ; Npad = NPAD_IN;
  } else if (b < 6400) {              // out_proj: 4 layers x (16 x 32), fold gnorm_w over K
    int r = b - 4352; int z = r / 512; r %= 512;
    bx = r % 16; by = r / 16;
    W = W_out + (size_t)z * D_INNER * D_MODEL;
    fold = gnorm_w + (size_t)z * D_INNER;
    Wt = WtOut + (size_t)z * D_MODEL * D_INNER;
    K = D_INNER; N = D_MODEL; Npad = D_MODEL;
  } else {                            // head: 2 x 16, no fold
    int r = b - 6400;
    bx = r % 2; by = r / 2;
    W = head_w; fold = nullptr; Wt = WtHead;
    K = D_MODEL; N = VOCAB; Npad = NPAD_HEAD;
  }
  __shared__ float T[32][33];
  int n0 = bx * 32, k0 = by * 32;
  int tx = threadIdx.x & 31, ty = threadIdx.x >> 5;  // ty 0..7
  #pragma unroll
  for (int i = 0; i < 4; i++) {
    int n = n0 + tx;
    T[ty + i * 8][tx] = (n < N) ? W[(size_t)(k0 + ty + i * 8) * N + n] : 0.f;
  }
  __syncthreads();
  float fs = fold ? fold[k0 + tx] : 1.f;
  #pragma unroll
  for (int i = 0; i < 4; i++)
    Wt[(size_t)(n0 + ty + i * 8) * K + k0 + tx] = (__bf16)(T[tx][ty + i * 8] * fs);
}

// ------- bf16 MFMA GEMM, 64x32 tile, TRI-buffered depth-2 pipeline (out_proj / head) -------
// Longest-K kernel: depth-2 counted vmcnt keeps 2 tiles in flight across barriers.
// 3 gloads/thread per stage (A 2 + B 1): steady vmcnt(6), drain vmcnt(3)/(0).
// LDS 3x12KB=36KB -> 4 blocks/CU; grid 1024 (out_proj) = full single scheduling round.
#define TK 64
__global__ __launch_bounds__(256) void gemm64_kernel(
    const __bf16* __restrict__ A, const __bf16* __restrict__ Bt,
    const float* __restrict__ bias, const float* __restrict__ res,
    float* __restrict__ C, __bf16* __restrict__ Cbf,
    float inv_norm_dim, int nbx, int K, int N, int ldc) {
  __shared__ __bf16 As[3][64 * TK];
  __shared__ __bf16 Bs[3][32 * TK];
  int tid = threadIdx.x;
  int lane = tid & 63, wave = tid >> 6;
  int wm = wave >> 1, wn = wave & 1;        // wm 0..1 (row half), wn 0..1 (16-col half)
  int q = lane >> 4, l16 = lane & 15;
  int lin = xcd_lin();
  int bx = lin % nbx, by = lin / nbx;
  size_t row0 = (size_t)by * 64;
  int col0 = bx * 32;
  const __bf16* Ab = A + row0 * K;
  const __bf16* Bb = Bt + (size_t)col0 * K;

  auto stage = [&](int buf, int kk) {
    #pragma unroll
    for (int r = 0; r < 2; r++) {           // A: 64 rows x 64 K = 8KB = 2 x 16B/thread
      int lin2 = r * 256 + tid;
      gload_lds16(Ab + (size_t)(lin2 >> 3) * K + kk + (lin2 & 7) * 8, &As[buf][lin2 * 8]);
    }
    {                                        // B: 32 rows x 64 K = 4KB = 1 x 16B/thread
      int lin2 = tid;
      gload_lds16(Bb + (size_t)(lin2 >> 3) * K + kk + (lin2 & 7) * 8, &Bs[buf][lin2 * 8]);
    }
  };

  f32x4 acc[2];
  acc[0] = (f32x4){0.f, 0.f, 0.f, 0.f};
  acc[1] = (f32x4){0.f, 0.f, 0.f, 0.f};
  float ssqa[2] = {0.f, 0.f};

  int niter = K / TK;
  stage(0, 0);
  if (niter > 1) stage(1, TK);
  int bi = 0;
  for (int i = 0; i < niter; i++) {
    if (i + 2 < niter) {
      stage((bi + 2) % 3, (i + 2) * TK);    // issue 2 ahead
      asm volatile("s_waitcnt vmcnt(6)" ::: "memory");   // tile i done; i+1,i+2 in flight
    } else if (i + 1 < niter) {
      asm volatile("s_waitcnt vmcnt(3)" ::: "memory");   // tile i done; i+1 in flight
    } else {
      asm volatile("s_waitcnt vmcnt(0)" ::: "memory");
    }
    __builtin_amdgcn_s_barrier();
    #pragma unroll
    for (int ks = 0; ks < 2; ks++) {
      bf16x8 af[2], bfv;
      #pragma unroll
      for (int ii = 0; ii < 2; ii++) {
        af[ii] = *(const bf16x8*)(&As[bi][(wm * 32 + ii * 16 + l16) * TK + ks * 32 + q * 8]);
        #pragma unroll
        for (int k = 0; k < 8; k++) { float v = (float)af[ii][k]; ssqa[ii] += v * v; }
      }
      bfv = *(const bf16x8*)(&Bs[bi][(wn * 16 + l16) * TK + ks * 32 + q * 8]);
      #pragma unroll
      for (int ii = 0; ii < 2; ii++)
        acc[ii] = __builtin_amdgcn_mfma_f32_16x16x32_bf16(af[ii], bfv, acc[ii], 0, 0, 0);
    }
    __builtin_amdgcn_s_barrier();           // all reads of slot bi done before its re-stage
    bi = (bi + 1) % 3;
  }

  #pragma unroll
  for (int i = 0; i < 2; i++) {
    ssqa[i] += __shfl_xor(ssqa[i], 16);
    ssqa[i] += __shfl_xor(ssqa[i], 32);     // full row sum for row wm*32+i*16+l16
  }
  #pragma unroll
  for (int i = 0; i < 2; i++) {
    #pragma unroll
    for (int rr = 0; rr < 4; rr++) {
      size_t mrow = row0 + wm * 32 + i * 16 + q * 4 + rr;
      float sq = __shfl(ssqa[i], q * 4 + rr);
      float sc = (inv_norm_dim > 0.f) ? rsqrtf(sq * inv_norm_dim + EPS) : 1.f;
      int col = col0 + wn * 16 + l16;
      if (col < N) {
        size_t off = mrow * (size_t)ldc + col;
        float v = acc[i][rr] * sc + (bias ? bias[col] : 0.f);
        if (res) v += res[off];
        if (C)   C[off] = v;
        if (Cbf) Cbf[off] = (__bf16)v;
      }
    }
  }
}

// ------- bf16 MFMA GEMM, 64x128 tile (in_proj) -------
// A single-buffered (staged post-MFMA), B double-buffered: LDS = 40KB -> 4 blocks/CU
// rmsnorm fused via in-kernel row-ssq; epilogue repacked through LDS -> bf16x8 stores
// (R13 lesson: deeper K-step-32 tri-buffer regressed here -- short K-chain, barrier
//  overhead dominates; this depth-1 TK=64 form is the measured best.)
__global__ __launch_bounds__(256) void gemm_in_kernel(
    const __bf16* __restrict__ A, const __bf16* __restrict__ Bt,
    const float* __restrict__ bias, __bf16* __restrict__ Cbf,
    int nbx, int K, int N, int ldc) {
  __shared__ __bf16 As[64 * TK];
  __shared__ __bf16 Bs[2][128 * TK];
  int tid = threadIdx.x;
  int lane = tid & 63, wave = tid >> 6;
  int wm = wave >> 1, wn = wave & 1;
  int q = lane >> 4, l16 = lane & 15;
  int lin = xcd_lin();
  int bx = lin % nbx, by = lin / nbx;
  size_t row0 = (size_t)by * 64;
  int col0 = bx * 128;
  const __bf16* Ab = A + row0 * K;
  const __bf16* Bb = Bt + (size_t)col0 * K;

  auto stageA = [&](int kk) {
    #pragma unroll
    for (int r = 0; r < 2; r++) {
      int lin2 = r * 256 + tid;
      gload_lds16(Ab + (size_t)(lin2 >> 3) * K + kk + (lin2 & 7) * 8, As + lin2 * 8);
    }
  };
  auto stageB = [&](int buf, int kk) {
    #pragma unroll
    for (int r = 0; r < 4; r++) {
      int lin2 = r * 256 + tid;
      gload_lds16(Bb + (size_t)(lin2 >> 3) * K + kk + (lin2 & 7) * 8, &Bs[buf][lin2 * 8]);
    }
  };

  f32x4 acc[2][4];
  #pragma unroll
  for (int i = 0; i < 2; i++)
    #pragma unroll
    for (int j = 0; j < 4; j++) acc[i][j] = (f32x4){0.f, 0.f, 0.f, 0.f};
  float ssqa[2] = {0.f, 0.f};

  stageA(0);
  stageB(0, 0);
  int cur = 0;
  for (int k0 = 0; k0 < K; k0 += TK) {
    if (k0 + TK < K) {
      stageB(cur ^ 1, k0 + TK);                     // B one iteration ahead
      asm volatile("s_waitcnt vmcnt(4)" ::: "memory");  // A(k)+B(k) done; B(k+1) in flight
    } else {
      asm volatile("s_waitcnt vmcnt(0)" ::: "memory");
    }
    __builtin_amdgcn_s_barrier();
    #pragma unroll
    for (int ks = 0; ks < 2; ks++) {
      bf16x8 af[2], bfv[4];
      #pragma unroll
      for (int i = 0; i < 2; i++) {
        af[i] = *(const bf16x8*)(&As[(wm * 32 + i * 16 + l16) * TK + ks * 32 + q * 8]);
        #pragma unroll
        for (int k = 0; k < 8; k++) { float v = (float)af[i][k]; ssqa[i] += v * v; }
      }
      #pragma unroll
      for (int j = 0; j < 4; j++)
        bfv[j] = *(const bf16x8*)(&Bs[cur][(wn * 64 + j * 16 + l16) * TK + ks * 32 + q * 8]);
      #pragma unroll
      for (int i = 0; i < 2; i++)
        #pragma unroll
        for (int j = 0; j < 4; j++)
          acc[i][j] = __builtin_amdgcn_mfma_f32_16x16x32_bf16(af[i], bfv[j], acc[i][j], 0, 0, 0);
    }
    __builtin_amdgcn_s_barrier();
    if (k0 + TK < K) stageA(k0 + TK);               // safe: all As reads drained by barrier
    cur ^= 1;
  }

  #pragma unroll
  for (int i = 0; i < 2; i++) {
    ssqa[i] += __shfl_xor(ssqa[i], 16);
    ssqa[i] += __shfl_xor(ssqa[i], 32);
  }
  // epilogue: scale+bias -> LDS (bf16) -> coalesced bf16x8 stores
  __bf16* Cs = (__bf16*)Bs;            // dead; 64x136 = 17408 B fits in Bs
  const int CST = 136;
  float bvj[4];
  #pragma unroll
  for (int j = 0; j < 4; j++) {
    int colj = col0 + wn * 64 + j * 16 + l16;
    bvj[j] = (colj < N) ? bias[colj] : 0.f;
  }
  #pragma unroll
  for (int i = 0; i < 2; i++) {
    #pragma unroll
    for (int rr = 0; rr < 4; rr++) {
      int rloc = wm * 32 + i * 16 + q * 4 + rr;
      float sq = __shfl(ssqa[i], q * 4 + rr);
      float sc = rsqrtf(sq * (1.f / D_MODEL) + EPS);
      #pragma unroll
      for (int j = 0; j < 4; j++)
        Cs[rloc * CST + wn * 64 + j * 16 + l16] = (__bf16)(acc[i][j][rr] * sc + bvj[j]);
    }
  }
  __syncthreads();
  #pragma unroll
  for (int s = 0; s < 2; s++) {
    int idx = s * 256 + tid;
    int row = idx >> 3, c0 = (idx & 7) * 16;
    if (col0 + c0 < N) {
      bf16x8 v0 = *(const bf16x8*)(&Cs[row * CST + c0]);
      bf16x8 v1 = *(const bf16x8*)(&Cs[row * CST + c0 + 8]);
      __bf16* dst = Cbf + (row0 + row) * (size_t)ldc + col0 + c0;
      *(bf16x8*)dst = v0;
      *(bf16x8*)(dst + 8) = v1;
    }
  }
}

// ================= MFMA chunked SSD (split pair, conv once, image-layout cache) =================
// zxbf row: [z 0..1024 | x 1024..2048 | B 2048..2080 | C 2080..2112 | dt 2112..2128]
// ssd_local: conv/silu + dt-cumsum; caches conv outputs as EXACT LDS IMAGES
// (lxT padded [64][PSTR]; lB|lC contiguous [64][32]x2) so ssd_out can DMA them
// linearly with global_load_lds; publishes Slocal (chunks 0..NC-2 only; Slocal of the
// last chunk is never read) + dAprod.
// ssd_out: async-stages the images, overlaps the chunk-start scan with the DMA.
__device__ __forceinline__ void wave0_dt_cumsum(
    const __bf16* __restrict__ zxbf, const float* __restrict__ dt_bias,
    int b, int h, int t0, int tid, float* ldt, float* lcs, float* __restrict__ dtcsg) {
  if (tid < 64) {
    float dv = (float)zxbf[((size_t)(b * SEQ + t0 + tid)) * D_IN_PROJ + 2 * D_INNER + 2 * N_STATE + h]
               + dt_bias[h];
    float dtv = softplusf_(dv);
    float cs = dtv;
    #pragma unroll
    for (int off = 1; off < 64; off <<= 1) {
      float o = __shfl_up(cs, off);
      if (tid >= off) cs += o;
    }
    ldt[tid] = dtv;
    lcs[tid] = cs;
    dtcsg[tid] = dtv;
    dtcsg[64 + tid] = cs;
  }
}

__global__ __launch_bounds__(256) void ssd_local_kernel(
    const __bf16* __restrict__ zxbf, const float* __restrict__ conv_w,
    const float* __restrict__ conv_b, const float* __restrict__ dt_bias,
    const float* __restrict__ A_log,
    float* __restrict__ Slocal, float* __restrict__ dAprod,
    __bf16* __restrict__ convx, __bf16* __restrict__ convbc, float* __restrict__ dtcs) {
  int blk = xcd_lin();
  int c = blk % NC;
  int h = (blk / NC) % H_HEADS;
  int b = blk / (NC * H_HEADS);
  int tid = threadIdx.x;
  int lane = tid & 63, wave = tid >> 6;
  int q = lane >> 4, l16 = lane & 15;
  int t0 = c * CL;
  float A = -__expf(A_log[h]);
  __shared__ __bf16 rawbuf[2 * 68 * 64];   // rawx | rawBC; reused as f32 sT[64][36]
  __shared__ __bf16 lxT[64][PSTR];
  __shared__ __bf16 lBTw[32][PSTR];
  __shared__ float ldt[64], lcs[64];
  __bf16* rawx = rawbuf;
  __bf16* rawBC = rawbuf + 68 * 64;
  for (int i = tid; i < 68 * 8; i += 256) {
    int r = i >> 3, c0 = (i & 7) * 8;
    int gr = t0 - 3 + r;
    bf16x8 vx, vbc;
    #pragma unroll
    for (int k = 0; k < 8; k++) { vx[k] = (__bf16)0.f; vbc[k] = (__bf16)0.f; }
    if (gr >= 0) {
      const __bf16* rowp = zxbf + ((size_t)(b * SEQ + gr)) * D_IN_PROJ;
      vx  = *(const bf16x8*)(rowp + D_INNER + h * 64 + c0);
      vbc = *(const bf16x8*)(rowp + 2 * D_INNER + c0);
    }
    *(bf16x8*)(rawx + r * 64 + c0)  = vx;
    *(bf16x8*)(rawBC + r * 64 + c0) = vbc;
  }
  wave0_dt_cumsum(zxbf, dt_bias, b, h, t0, tid, ldt, lcs, dtcs + (size_t)blk * 128);
  __syncthreads();
  float cs63 = lcs[63];
  __bf16* xg  = convx  + (size_t)blk * (64 * PSTR);
  __bf16* bcg = convbc + (size_t)blk * 4096;
  // conv x -> lxT (transposed, silu)
  {
    int p = tid & 63;
    const float* w = conv_w + (h * 64 + p) * K_CONV;
    float w0 = w[0], w1 = w[1], w2 = w[2], w3 = w[3];
    float cb = conv_b[h * 64 + p];
    for (int i = tid; i < CL * 64; i += 256) {
      int t = i >> 6;
      float a = cb + w0 * (float)rawx[t * 64 + p] + w1 * (float)rawx[(t + 1) * 64 + p]
                   + w2 * (float)rawx[(t + 2) * 64 + p] + w3 * (float)rawx[(t + 3) * 64 + p];
      lxT[p][t] = (__bf16)(a * sigmoidf_(a));
    }
  }
  // conv B,C -> cache image (row-major); B also weighted into lBTw for the Slocal MFMA
  {
    int col = tid & 63;
    const float* w = conv_w + (D_INNER + col) * K_CONV;
    float w0 = w[0], w1 = w[1], w2 = w[2], w3 = w[3];
    float cb = conv_b[D_INNER + col];
    for (int i = tid; i < CL * 64; i += 256) {
      int t = i >> 6;
      float a = cb + w0 * (float)rawBC[t * 64 + col] + w1 * (float)rawBC[(t + 1) * 64 + col]
                   + w2 * (float)rawBC[(t + 2) * 64 + col] + w3 * (float)rawBC[(t + 3) * 64 + col];
      float v = a * sigmoidf_(a);
      if (col < 32) {
        bcg[t * 32 + col] = (__bf16)v;
        float wt = ldt[t] * __expf(A * (cs63 - lcs[t]));
        lBTw[col][t] = (__bf16)(v * wt);
      } else {
        bcg[2048 + t * 32 + (col - 32)] = (__bf16)v;
      }
    }
  }
  __syncthreads();
  // cache the padded lxT image verbatim (incl. pad bytes; never read)
  for (int i = tid; i < (64 * PSTR) / 8; i += 256)
    *(bf16x8*)(xg + i * 8) = *(const bf16x8*)(((const __bf16*)lxT) + i * 8);
  // Slocal = xT(weighted-B)^T via MFMA -- only chunks whose Slocal is ever read (c < NC-1)
  if (c < NC - 1) {
    f32x4 acc0 = (f32x4){0.f,0.f,0.f,0.f}, acc1 = (f32x4){0.f,0.f,0.f,0.f};
    #pragma unroll
    for (int kb = 0; kb < 2; kb++) {
      bf16x8 af = *(const bf16x8*)(&lxT[wave * 16 + l16][kb * 32 + q * 8]);
      bf16x8 b0 = *(const bf16x8*)(&lBTw[l16][kb * 32 + q * 8]);
      bf16x8 b1 = *(const bf16x8*)(&lBTw[l16 + 16][kb * 32 + q * 8]);
      acc0 = __builtin_amdgcn_mfma_f32_16x16x32_bf16(af, b0, acc0, 0, 0, 0);
      acc1 = __builtin_amdgcn_mfma_f32_16x16x32_bf16(af, b1, acc1, 0, 0, 0);
    }
    // LDS bounce (wave-private rows) -> f32x4 stores
    float* sT = (float*)rawbuf;
    #pragma unroll
    for (int rr = 0; rr < 4; rr++) {
      int p = wave * 16 + q * 4 + rr;
      sT[p * 36 + l16]      = acc0[rr];
      sT[p * 36 + l16 + 16] = acc1[rr];
    }
    int row = tid >> 2, c0 = (tid & 3) * 8;
    f32x4 a = *(const f32x4*)(sT + row * 36 + c0);
    f32x4 b2 = *(const f32x4*)(sT + row * 36 + c0 + 4);
    float* dstp = Slocal + (size_t)blk * 2048 + row * 32 + c0;
    *(f32x4*)dstp = a;
    *(f32x4*)(dstp + 4) = b2;
  }
  if (tid == 0) dAprod[blk] = __expf(A * cs63);
}

__global__ __launch_bounds__(256) void ssd_out_kernel(
    const __bf16* __restrict__ zxbf, const float* __restrict__ A_log,
    const float* __restrict__ Dp,
    const float* __restrict__ Slocal, const float* __restrict__ dAprod,
    const __bf16* __restrict__ convx, const __bf16* __restrict__ convbc,
    const float* __restrict__ dtcs, __bf16* __restrict__ gout) {
  int blk = xcd_lin();
  int c = blk % NC;
  int h = (blk / NC) % H_HEADS;
  int b = blk / (NC * H_HEADS);
  int tid = threadIdx.x;
  int lane = tid & 63, wave = tid >> 6;
  int q = lane >> 4, l16 = lane & 15;
  int t0 = c * CL;
  float A = -__expf(A_log[h]);
  float D = Dp[h];
  __shared__ __bf16 lxT[64][PSTR];
  __shared__ __bf16 pPbuf[64 * PSTR];       // per-wave P slabs; reused as yT[64][72]
  __shared__ __bf16 lBC[2 * 64 * 32];       // lB | lC contiguous (matches bcg image)
  __shared__ __bf16 lS[64][32];
  __shared__ float ldt[64], lcs[64];
  const __bf16* xg  = convx  + (size_t)blk * (64 * PSTR);
  const __bf16* bcg = convbc + (size_t)blk * 4096;
  __bf16* lB = lBC;
  __bf16* lC = lBC + 2048;
  // async DMA the conv-cache images into LDS (linear dest, wave-contiguous)
  for (int i = tid; i < (64 * PSTR) / 8; i += 256)
    gload_lds16(xg + i * 8, ((__bf16*)lxT) + i * 8);
  for (int i = tid; i < 512; i += 256)
    gload_lds16(bcg + i * 8, lBC + i * 8);
  // overlap: small loads + the serial prefix scan hide the DMA latency
  if (tid < 64) {
    const float* dg = dtcs + (size_t)blk * 128;
    ldt[tid] = dg[tid];
    lcs[tid] = dg[64 + tid];
  }
  // chunk-start scan: Sstart_c = scan over Slocal chunks j<c.
  // dAprod read directly from global per thread (L2-hot broadcast) -- no LDS pr[]
  // (an LDS pr[] here would need a barrier, which would drain the DMA early; direct
  // loads keep the DMA overlapped AND avoid the cross-thread race).
  {
    int p = tid >> 2, n0 = (tid & 3) * 8;
    const float* sl = Slocal + (size_t)(blk - c) * 2048 + p * 32 + n0;
    const float* dab = dAprod + (blk - c);
    float st[8] = {};
    for (int j = 0; j < c; j++) {
      f32x4 a = *(const f32x4*)(sl + (size_t)j * 2048);
      f32x4 bq = *(const f32x4*)(sl + (size_t)j * 2048 + 4);
      float prj = dab[j];
      #pragma unroll
      for (int k = 0; k < 4; k++) { st[k] = prj * st[k] + a[k]; st[4 + k] = prj * st[4 + k] + bq[k]; }
    }
    #pragma unroll
    for (int k = 0; k < 8; k++) lS[p][n0 + k] = (__bf16)st[k];
  }
  __syncthreads();   // drains DMA (vmcnt) + all LDS writes
  bf16x8 afC = *(const bf16x8*)(lC + (wave * 16 + l16) * 32 + q * 8);
  f32x4 accG[4], accI[4], accY[4];
  #pragma unroll
  for (int j = 0; j < 4; j++) {
    accG[j] = (f32x4){0.f,0.f,0.f,0.f};
    accI[j] = (f32x4){0.f,0.f,0.f,0.f};
    accY[j] = (f32x4){0.f,0.f,0.f,0.f};
  }
  #pragma unroll
  for (int j = 0; j < 4; j++) {
    bf16x8 bf = *(const bf16x8*)(lB + (l16 + 16 * j) * 32 + q * 8);
    accG[j] = __builtin_amdgcn_mfma_f32_16x16x32_bf16(afC, bf, accG[j], 0, 0, 0);
  }
  #pragma unroll
  for (int j = 0; j < 4; j++) {
    bf16x8 bf = *(const bf16x8*)(&lS[l16 + 16 * j][q * 8]);
    accI[j] = __builtin_amdgcn_mfma_f32_16x16x32_bf16(afC, bf, accI[j], 0, 0, 0);
  }
  __bf16* pP = pPbuf + wave * 16 * PSTR;    // wave-private slab
  #pragma unroll
  for (int j = 0; j < 4; j++) {
    int s = l16 + 16 * j;
    float css = lcs[s], dts = ldt[s];
    #pragma unroll
    for (int rr = 0; rr < 4; rr++) {
      int tl = q * 4 + rr;
      int t = wave * 16 + tl;
      float val = accG[j][rr] * __expf(A * (lcs[t] - css)) * dts;
      if (s == t) val += D;
      if (s > t) val = 0.f;
      pP[tl * PSTR + s] = (__bf16)val;
    }
  }
  #pragma unroll
  for (int kb = 0; kb < 2; kb++) {
    bf16x8 afP = *(const bf16x8*)(pP + l16 * PSTR + kb * 32 + q * 8);
    #pragma unroll
    for (int j = 0; j < 4; j++) {
      bf16x8 bf = *(const bf16x8*)(&lxT[l16 + 16 * j][kb * 32 + q * 8]);
      accY[j] = __builtin_amdgcn_mfma_f32_16x16x32_bf16(afP, bf, accY[j], 0, 0, 0);
    }
  }
  // y tile via LDS bounce (yT[64][72] over pPbuf; barrier: yT overlaps other waves' pP)
  __syncthreads();
  __bf16* yT = pPbuf;
  #pragma unroll
  for (int rr = 0; rr < 4; rr++) {
    int t = wave * 16 + q * 4 + rr;
    float cumt = __expf(A * lcs[t]);
    #pragma unroll
    for (int j = 0; j < 4; j++) {
      int p = l16 + 16 * j;
      yT[t * 72 + p] = (__bf16)(accY[j][rr] + cumt * accI[j][rr]);
    }
  }
  {
    int row = tid >> 2, col0 = (tid & 3) * 16;   // rows wave-private: no barrier needed
    bf16x8 y0 = *(const bf16x8*)(yT + row * 72 + col0);
    bf16x8 y1 = *(const bf16x8*)(yT + row * 72 + col0 + 8);
    const __bf16* zrow = zxbf + ((size_t)(b * SEQ + t0 + row)) * D_IN_PROJ + h * 64 + col0;
    bf16x8 z0 = *(const bf16x8*)zrow;
    bf16x8 z1 = *(const bf16x8*)(zrow + 8);
    bf16x8 g0, g1;
    #pragma unroll
    for (int k = 0; k < 8; k++) {
      float zz = (float)z0[k];
      g0[k] = (__bf16)((float)y0[k] * zz * sigmoidf_(zz));
    }
    #pragma unroll
    for (int k = 0; k < 8; k++) {
      float zz = (float)z1[k];
      g1[k] = (__bf16)((float)y1[k] * zz * sigmoidf_(zz));
    }
    __bf16* grow = gout + ((size_t)(b * SEQ + t0 + row)) * D_INNER + h * 64 + col0;
    *(bf16x8*)grow = g0;
    *(bf16x8*)(grow + 8) = g1;
  }
}

extern "C" void kernel_launch(void* const* d_in, const int* in_sizes, int n_in,
                              void* d_out, int out_size, void* d_ws, size_t ws_size,
                              hipStream_t stream) {
  const int*   tok     = (const int*)  d_in[0];
  const float* emb     = (const float*)d_in[1];
  const float* norm_w  = (const float*)d_in[2];
  const float* W_in    = (const float*)d_in[3];
  const float* b_in    = (const float*)d_in[4];
  const float* conv_w  = (const float*)d_in[5];
  const float* conv_b  = (const float*)d_in[6];
  const float* dt_bias = (const float*)d_in[7];
  const float* A_log   = (const float*)d_in[8];
  const float* D_par   = (const float*)d_in[9];
  const float* gnorm_w = (const float*)d_in[10];
  const float* W_out   = (const float*)d_in[11];
  const float* b_out   = (const float*)d_in[12];
  const float* head_w  = (const float*)d_in[13];
  const float* head_b  = (const float*)d_in[14];
  float* out = (float*)d_out;

  char* p = (char*)d_ws;
  auto alloc = [&](size_t bytes) { void* r = (void*)p; p += (bytes + 255) & ~(size_t)255; return r; };
  float*  h      = (float*) alloc((size_t)NTOK * D_MODEL * 4);
  float*  slocal = (float*) alloc((size_t)BATCH * H_HEADS * NC * P_HEAD * N_STATE * 4);
  float*  daprod = (float*) alloc((size_t)BATCH * H_HEADS * NC * 4);
  float*  dtcs   = (float*) alloc((size_t)1024 * 128 * 4);
  __bf16* convx  = (__bf16*)alloc((size_t)1024 * 64 * PSTR * 2);
  __bf16* convbc = (__bf16*)alloc((size_t)1024 * 4096 * 2);
  __bf16* zxbf   = (__bf16*)alloc((size_t)NTOK * D_IN_PROJ * 2);
  __bf16* gbf    = (__bf16*)alloc((size_t)NTOK * D_INNER * 2);
  __bf16* hbf    = (__bf16*)alloc((size_t)NTOK * D_MODEL * 2);
  __bf16* WtIn   = (__bf16*)alloc((size_t)LAYERS * NPAD_IN * D_MODEL * 2);
  __bf16* WtOut  = (__bf16*)alloc((size_t)LAYERS * D_MODEL * D_INNER * 2);
  __bf16* WtHead = (__bf16*)alloc((size_t)NPAD_HEAD * D_MODEL * 2);

  prep_kernel<<<6432 + NTOK / 4, 256, 0, stream>>>(
      W_in, W_out, head_w, norm_w, gnorm_w, WtIn, WtOut, WtHead,
      tok, emb, h, hbf);

  for (int l = 0; l < LAYERS; l++) {
    gemm_in_kernel<<<1088, 256, 0, stream>>>(
        hbf, WtIn + (size_t)l * NPAD_IN * D_MODEL, b_in + (size_t)l * D_IN_PROJ,
        zxbf, NPAD_IN / 128, D_MODEL, D_IN_PROJ, D_IN_PROJ);

    ssd_local_kernel<<<BATCH * H_HEADS * NC, 256, 0, stream>>>(
        zxbf, conv_w + (size_t)l * CONV_DIM * K_CONV, conv_b + (size_t)l * CONV_DIM,
        dt_bias + (size_t)l * H_HEADS, A_log + (size_t)l * H_HEADS, slocal, daprod,
        convx, convbc, dtcs);
    ssd_out_kernel<<<BATCH * H_HEADS * NC, 256, 0, stream>>>(
        zxbf, A_log + (size_t)l * H_HEADS, D_par + (size_t)l * H_HEADS,
        slocal, daprod, convx, convbc, dtcs, gbf);

    // out_proj: grid 1024 = 4 blocks/CU, 64x32 tiles, depth-2 pipeline
    gemm64_kernel<<<1024, 256, 0, stream>>>(
        gbf, WtOut + (size_t)l * D_MODEL * D_INNER, b_out + (size_t)l * D_MODEL, h,
        h, hbf, 1.f / D_INNER, D_MODEL / 32, D_INNER, D_MODEL, D_MODEL);
  }

  // head: grid 128, 64x32 tiles
  gemm64_kernel<<<128, 256, 0, stream>>>(
      hbf, WtHead, head_b, nullptr, out, nullptr, 0.f, NPAD_HEAD / 32, D_MODEL, VOCAB, VOCAB);
}